// Round 6
// baseline (248.247 us; speedup 1.0000x reference)
//
#include <hip/hip_runtime.h>

// SpatialNonIntersectionAxiom: B=8, N=512, E=4096.
// Outputs (flat f32): [0] = loss, [1 .. 1+E*E) = violation_mask (0/1),
// [1+E*E .. 1+2*E*E) = violation_scores.
//
// Strategy: mask=0 => both outputs exactly 0 (score = relu(..)*mask).
// Phase A zero-fills outputs, evaluates only the cheap candidate mask
// (bitwise-identical to reference) and stream-compacts masked pair ids.
// Phase B runs the expensive segment-distance only on masked pairs (~3%).

#define EDGES   4096
#define LOGE    12
#define EPS     0.001f
#define PROX    0.15f
#define NBUCKET 2048
#define ITILE   8
#define JBLK    512

// ---------------- per-edge precompute (E=4096 threads) ----------------
// rec1 = {a1x, a1y, d1x, d1y}
// rec2 = {midx, midy, half, dda(=d1.a1)}
// rec3 = {sq, bitcast(src), bitcast(dst), 0}
__global__ __launch_bounds__(256) void edge_pre(
    const float2* __restrict__ pos,
    const int*    __restrict__ esrc,
    const int*    __restrict__ edst,
    float4* __restrict__ rec1, float4* __restrict__ rec2, float4* __restrict__ rec3)
{
#pragma clang fp contract(off)
    const int e = blockIdx.x * 256 + threadIdx.x;
    const int s = esrc[e], d = edst[e];
    const float2 a1 = pos[s], a2 = pos[d];
    const float d1x = a2.x - a1.x, d1y = a2.y - a1.y;
    const float midx = (a1.x + a2.x) * 0.5f, midy = (a1.y + a2.y) * 0.5f;
    const float half = sqrtf(d1x * d1x + d1y * d1y) * 0.5f;
    const float sq   = fmaxf(d1x * d1x + d1y * d1y, 1e-12f);
    const float dda  = d1x * a1.x + d1y * a1.y;
    rec1[e] = make_float4(a1.x, a1.y, d1x, d1y);
    rec2[e] = make_float4(midx, midy, half, dda);
    rec3[e] = make_float4(sq, __int_as_float(s), __int_as_float(d), 0.0f);
}

// ---------------- phase A: zero-fill + mask eval + compaction ----------------
// grid = (8, 512): blockIdx.x = 512-col block, blockIdx.y = 8-row block.
__global__ __launch_bounds__(256) void mask_zero_compact(
    const float4* __restrict__ rec2, const float4* __restrict__ rec3,
    float*        __restrict__ out,
    unsigned*     __restrict__ gcount,
    unsigned*     __restrict__ wl)
{
#pragma clang fp contract(off)
    const int ibase = blockIdx.y * ITILE;
    const int jbase = blockIdx.x * JBLK;
    const int tid   = threadIdx.x;

    float* __restrict__ o_mask  = out + 1;
    float* __restrict__ o_score = out + 1 + EDGES * EDGES;

    const int j0 = jbase + tid;
    const int j1 = j0 + 256;

    // zero both planes for this tile (mandatory 134 MB total across grid)
    #pragma unroll
    for (int ii = 0; ii < ITILE; ++ii) {
        const int row = (ibase + ii) << LOGE;
        o_mask [row + j0] = 0.0f;  o_mask [row + j1] = 0.0f;
        o_score[row + j0] = 0.0f;  o_score[row + j1] = 0.0f;
    }
    if (jbase + JBLK - 1 <= ibase) return;   // no j > i pairs in this tile

    __shared__ unsigned lds_list[4][1024];   // per-wave append buffer (16 KB)
    const int wid  = tid >> 6, lane = tid & 63;
    const unsigned long long ltmask = (1ull << lane) - 1ull;

    const float4 r2j0 = rec2[j0], r3j0 = rec3[j0];
    const float4 r2j1 = rec2[j1], r3j1 = rec3[j1];
    const int sj0 = __float_as_int(r3j0.y), dj0 = __float_as_int(r3j0.z);
    const int sj1 = __float_as_int(r3j1.y), dj1 = __float_as_int(r3j1.z);

    unsigned wcount = 0;   // wave-uniform running count

    #pragma unroll
    for (int ii = 0; ii < ITILE; ++ii) {
        const int i = ibase + ii;                   // block-uniform
        const float4 r2i = rec2[i], r3i = rec3[i];
        const int si = __float_as_int(r3i.y), di = __float_as_int(r3i.z);

        {   // pair (i, j0) — mask path bitwise-identical to reference
            const float dmx = r2i.x - r2j0.x, dmy = r2i.y - r2j0.y;
            const float dist  = sqrtf(dmx * dmx + dmy * dmy);
            const float reach = r2i.z + r2j0.z + PROX;
            const bool shares = (si == sj0) | (si == dj0) | (di == sj0) | (di == dj0);
            const bool m = (dist < reach) & (j0 > i) & ((si >> 9) == (sj0 >> 9)) & (!shares);
            const unsigned long long b = __ballot(m);
            if (m) lds_list[wid][wcount + __popcll(b & ltmask)] = (unsigned)((i << LOGE) | j0);
            wcount += (unsigned)__popcll(b);
        }
        {   // pair (i, j1)
            const float dmx = r2i.x - r2j1.x, dmy = r2i.y - r2j1.y;
            const float dist  = sqrtf(dmx * dmx + dmy * dmy);
            const float reach = r2i.z + r2j1.z + PROX;
            const bool shares = (si == sj1) | (si == dj1) | (di == sj1) | (di == dj1);
            const bool m = (dist < reach) & (j1 > i) & ((si >> 9) == (sj1 >> 9)) & (!shares);
            const unsigned long long b = __ballot(m);
            if (m) lds_list[wid][wcount + __popcll(b & ltmask)] = (unsigned)((i << LOGE) | j1);
            wcount += (unsigned)__popcll(b);
        }
    }

    // reserve global space once per wave, copy out coalesced
    unsigned base0 = 0;
    if (lane == 0 && wcount) base0 = atomicAdd(gcount, wcount);
    base0 = (unsigned)__shfl((int)base0, 0, 64);
    for (unsigned u = lane; u < wcount; u += 64) wl[base0 + u] = lds_list[wid][u];
}

// ---------------- phase B: segment distance on masked pairs only ----------------
__global__ __launch_bounds__(256) void seg_kernel(
    const float4* __restrict__ rec1, const float4* __restrict__ rec2,
    const float4* __restrict__ rec3,
    const unsigned* __restrict__ gcount, const unsigned* __restrict__ wl,
    float* __restrict__ out, float* __restrict__ bsum)
{
#pragma clang fp contract(off)
    const unsigned n = *gcount;
    float* __restrict__ o_mask  = out + 1;
    float* __restrict__ o_score = out + 1 + EDGES * EDGES;

    float vsum = 0.0f;
    for (unsigned idx = blockIdx.x * 256 + threadIdx.x; idx < n; idx += gridDim.x * 256) {
        const unsigned k = wl[idx];
        const int i = (int)(k >> LOGE), j = (int)(k & (EDGES - 1));
        const float4 r1i = rec1[i], r2i = rec2[i], r3i = rec3[i];
        const float4 r1j = rec1[j], r2j = rec2[j], r3j = rec3[j];

        // reference op order, IEEE div/sqrt, no FMA (bitwise-identical)
        const float sqi = r3i.x, sqj = r3j.x;
        const float b = r1i.z * r1j.z + r1i.w * r1j.w;
        const float c = r2i.w - (r1i.z * r1j.x + r1i.w * r1j.y);
        const float f = (r1i.x * r1j.z + r1i.y * r1j.w) - r2j.w;
        const float denom = fmaxf(sqi * sqj - b * b, 1e-12f);

        float s = (b * f - c * sqj) / denom;
        s = fminf(fmaxf(s, 0.0f), 1.0f);
        const float t = fminf(fmaxf((b * s + f) / sqj, 0.0f), 1.0f);
        s = fminf(fmaxf((b * t - c) / sqi, 0.0f), 1.0f);

        const float cax = r1i.x + s * r1i.z, cay = r1i.y + s * r1i.w;
        const float cbx = r1j.x + t * r1j.z, cby = r1j.y + t * r1j.w;
        const float dx = cax - cbx, dy = cay - cby;
        const float dmin = sqrtf(dx * dx + dy * dy);

        const float pl = fmaxf(EPS - dmin, 0.0f);   // mask == 1 here
        if (pl > 0.0f) {
            o_mask[k]  = 1.0f;
            o_score[k] = pl;
            vsum += pl;
        }
    }

    #pragma unroll
    for (int off = 32; off > 0; off >>= 1) vsum += __shfl_xor(vsum, off, 64);
    const int wid = threadIdx.x >> 6, lane = threadIdx.x & 63;
    if (lane == 0 && vsum != 0.0f)
        atomicAdd(&bsum[(blockIdx.x * 4 + wid) & (NBUCKET - 1)], vsum);
}

__global__ __launch_bounds__(256) void finalize_kernel(
    const float* __restrict__ bsum, const unsigned* __restrict__ gcount,
    float* __restrict__ out)
{
    float s = 0.0f;
    for (int b = threadIdx.x; b < NBUCKET; b += 256) s += bsum[b];
    #pragma unroll
    for (int off = 32; off > 0; off >>= 1) s += __shfl_xor(s, off, 64);
    __shared__ float ls[4];
    const int wid = threadIdx.x >> 6, lane = threadIdx.x & 63;
    if (lane == 0) ls[wid] = s;
    __syncthreads();
    if (threadIdx.x == 0) {
        const float st = ls[0] + ls[1] + ls[2] + ls[3];
        const unsigned ct = *gcount;
        const unsigned n = ct > 1u ? ct : 1u;
        out[0] = st / (float)n;
    }
}

extern "C" void kernel_launch(void* const* d_in, const int* in_sizes, int n_in,
                              void* d_out, int out_size, void* d_ws, size_t ws_size,
                              hipStream_t stream) {
    const float2* pos  = (const float2*)d_in[0];   // node_positions (8,512,2)
    // d_in[1] = adjacency: unused
    const int*    esrc = (const int*)d_in[2];       // edge_index[0]
    const int*    edst = esrc + EDGES;              // edge_index[1]

    float*    out    = (float*)d_out;
    char*     ws     = (char*)d_ws;
    unsigned* gcount = (unsigned*)ws;                       // offset 0
    float*    bsum   = (float*)(ws + 1024);                 // 2048 floats
    unsigned* wl     = (unsigned*)(ws + (1u << 20));        // worklist, huge capacity
    float4*   rec1   = (float4*)(ws + (256u << 20));        // recs at 256 MB
    float4*   rec2   = rec1 + EDGES;
    float4*   rec3   = rec2 + EDGES;

    hipMemsetAsync(d_ws, 0, 16384, stream);                 // gcount + bsum

    edge_pre<<<EDGES / 256, 256, 0, stream>>>(pos, esrc, edst, rec1, rec2, rec3);
    dim3 grid(EDGES / JBLK, EDGES / ITILE);                 // (8, 512)
    mask_zero_compact<<<grid, 256, 0, stream>>>(rec2, rec3, out, gcount, wl);
    seg_kernel<<<512, 256, 0, stream>>>(rec1, rec2, rec3, gcount, wl, out, bsum);
    finalize_kernel<<<1, 256, 0, stream>>>(bsum, gcount, out);
}

// Round 7
// 182.141 us; speedup vs baseline: 1.3629x; 1.3629x over previous
//
#include <hip/hip_runtime.h>

// SpatialNonIntersectionAxiom: B=8, N=512, E=4096.
// Outputs (flat f32): [0] = loss, [1 .. 1+E*E) = violation_mask (0/1),
// [1+E*E .. 1+2*E*E) = violation_scores.
//
// Structure: (1) streaming contiguous zero-fill of both output planes at
// full HBM write BW; (2) mask kernel evaluates the cheap candidate mask,
// compacts masked pairs into a per-wave LDS list (no global atomics) and
// runs the expensive segment distance in-wave on the ~3% masked pairs,
// scatter-writing only nonzero results; (3) tiny finalize for the loss.

#define EDGES   4096
#define LOGE    12
#define EPS     0.001f
#define PROX    0.15f
#define NBUCKET 2048
#define ITILE   8
#define JBLK    512

// ---------------- per-edge precompute (E=4096 threads) ----------------
// rec1 = {a1x, a1y, d1x, d1y}
// rec2 = {midx, midy, half, dda(=d1.a1)}
// rec3 = {sq, bitcast(src), bitcast(dst), 0}
__global__ __launch_bounds__(256) void edge_pre(
    const float2* __restrict__ pos,
    const int*    __restrict__ esrc,
    const int*    __restrict__ edst,
    float4* __restrict__ rec1, float4* __restrict__ rec2, float4* __restrict__ rec3)
{
#pragma clang fp contract(off)
    const int e = blockIdx.x * 256 + threadIdx.x;
    const int s = esrc[e], d = edst[e];
    const float2 a1 = pos[s], a2 = pos[d];
    const float d1x = a2.x - a1.x, d1y = a2.y - a1.y;
    const float midx = (a1.x + a2.x) * 0.5f, midy = (a1.y + a2.y) * 0.5f;
    const float half = sqrtf(d1x * d1x + d1y * d1y) * 0.5f;
    const float sq   = fmaxf(d1x * d1x + d1y * d1y, 1e-12f);
    const float dda  = d1x * a1.x + d1y * a1.y;
    rec1[e] = make_float4(a1.x, a1.y, d1x, d1y);
    rec2[e] = make_float4(midx, midy, half, dda);
    rec3[e] = make_float4(sq, __int_as_float(s), __int_as_float(d), 0.0f);
}

// ---------------- streaming zero-fill of out[1 .. 2*E*E] ----------------
// Mimics fillBufferAligned: consecutive threads write consecutive float4s,
// each pass covers one contiguous 8 MB window. out+4 is 16B-aligned.
#define ZF_BLOCKS 2048
#define ZF_T      (ZF_BLOCKS * 256)          // 524288 threads
#define ZF_QUADS  8388607u                   // float4s in [4, 33554431]
__global__ __launch_bounds__(256) void zero_fill(float* __restrict__ out)
{
    const unsigned g = blockIdx.x * 256 + threadIdx.x;
    float4* __restrict__ base = (float4*)(out + 4);
    const float4 z4 = make_float4(0.0f, 0.0f, 0.0f, 0.0f);
    #pragma unroll
    for (unsigned p = 0; p < 16; ++p) {
        const unsigned idx = g + p * (unsigned)ZF_T;
        if (idx < ZF_QUADS) base[idx] = z4;
    }
    if (g == 0) {
        out[1] = 0.0f; out[2] = 0.0f; out[3] = 0.0f;
        out[2 * EDGES * EDGES] = 0.0f;       // last element (index 33554432)
    }
}

// -------- mask + in-wave segment distance on compacted pairs --------
// grid = (8, 512): blockIdx.x = 512-col block, blockIdx.y = 8-row block.
__global__ __launch_bounds__(256) void mask_seg(
    const float4* __restrict__ rec1, const float4* __restrict__ rec2,
    const float4* __restrict__ rec3,
    float*        __restrict__ out,
    float*        __restrict__ bsum,
    unsigned*     __restrict__ bcnt)
{
#pragma clang fp contract(off)
    const int ibase = blockIdx.y * ITILE;
    const int jbase = blockIdx.x * JBLK;
    const int tid   = threadIdx.x;

    if (jbase + JBLK - 1 <= ibase) return;    // no j > i pairs in this tile

    float* __restrict__ o_mask  = out + 1;
    float* __restrict__ o_score = out + 1 + EDGES * EDGES;

    __shared__ unsigned lds_list[4][1024];    // per-wave compaction buffer
    const int wid  = tid >> 6, lane = tid & 63;
    const unsigned long long ltmask = (1ull << lane) - 1ull;

    const int j0 = jbase + tid;
    const int j1 = j0 + 256;
    const float4 r2j0 = rec2[j0], r3j0 = rec3[j0];
    const float4 r2j1 = rec2[j1], r3j1 = rec3[j1];
    const int sj0 = __float_as_int(r3j0.y), dj0 = __float_as_int(r3j0.z);
    const int sj1 = __float_as_int(r3j1.y), dj1 = __float_as_int(r3j1.z);

    unsigned wcount = 0;   // wave-uniform running count

    #pragma unroll
    for (int ii = 0; ii < ITILE; ++ii) {
        const int i = ibase + ii;             // block-uniform
        const float4 r2i = rec2[i], r3i = rec3[i];
        const int si = __float_as_int(r3i.y), di = __float_as_int(r3i.z);

        {   // pair (i, j0) — mask path bitwise-identical to reference
            const float dmx = r2i.x - r2j0.x, dmy = r2i.y - r2j0.y;
            const float dist  = sqrtf(dmx * dmx + dmy * dmy);
            const float reach = r2i.z + r2j0.z + PROX;
            const bool shares = (si == sj0) | (si == dj0) | (di == sj0) | (di == dj0);
            const bool m = (dist < reach) & (j0 > i) & ((si >> 9) == (sj0 >> 9)) & (!shares);
            const unsigned long long b = __ballot(m);
            if (m) lds_list[wid][wcount + __popcll(b & ltmask)] = (unsigned)((i << LOGE) | j0);
            wcount += (unsigned)__popcll(b);
        }
        {   // pair (i, j1)
            const float dmx = r2i.x - r2j1.x, dmy = r2i.y - r2j1.y;
            const float dist  = sqrtf(dmx * dmx + dmy * dmy);
            const float reach = r2i.z + r2j1.z + PROX;
            const bool shares = (si == sj1) | (si == dj1) | (di == sj1) | (di == dj1);
            const bool m = (dist < reach) & (j1 > i) & ((si >> 9) == (sj1 >> 9)) & (!shares);
            const unsigned long long b = __ballot(m);
            if (m) lds_list[wid][wcount + __popcll(b & ltmask)] = (unsigned)((i << LOGE) | j1);
            wcount += (unsigned)__popcll(b);
        }
    }

    // ---- full segment distance, in-wave, on compacted pairs only ----
    float vsum = 0.0f;
    for (unsigned u = lane; u < wcount; u += 64) {
        const unsigned k = lds_list[wid][u];
        const int i = (int)(k >> LOGE), j = (int)(k & (EDGES - 1));
        const float4 r1i = rec1[i], r2i = rec2[i], r3i = rec3[i];
        const float4 r1j = rec1[j], r2j = rec2[j], r3j = rec3[j];

        // reference op order, IEEE div/sqrt, no FMA (bitwise-identical)
        const float sqi = r3i.x, sqj = r3j.x;
        const float b = r1i.z * r1j.z + r1i.w * r1j.w;
        const float c = r2i.w - (r1i.z * r1j.x + r1i.w * r1j.y);
        const float f = (r1i.x * r1j.z + r1i.y * r1j.w) - r2j.w;
        const float denom = fmaxf(sqi * sqj - b * b, 1e-12f);

        float s = (b * f - c * sqj) / denom;
        s = fminf(fmaxf(s, 0.0f), 1.0f);
        const float t = fminf(fmaxf((b * s + f) / sqj, 0.0f), 1.0f);
        s = fminf(fmaxf((b * t - c) / sqi, 0.0f), 1.0f);

        const float cax = r1i.x + s * r1i.z, cay = r1i.y + s * r1i.w;
        const float cbx = r1j.x + t * r1j.z, cby = r1j.y + t * r1j.w;
        const float dx = cax - cbx, dy = cay - cby;
        const float dmin = sqrtf(dx * dx + dy * dy);

        const float pl = fmaxf(EPS - dmin, 0.0f);   // mask == 1 here
        if (pl > 0.0f) {
            o_mask[k]  = 1.0f;
            o_score[k] = pl;
            vsum += pl;
        }
    }

    // ---- block reduction: sum(pair_loss), count(mask) ----
    #pragma unroll
    for (int off = 32; off > 0; off >>= 1) vsum += __shfl_xor(vsum, off, 64);
    __shared__ float    ls[4];
    __shared__ unsigned lc[4];
    if (lane == 0) { ls[wid] = vsum; lc[wid] = wcount; }
    __syncthreads();
    if (tid == 0) {
        const float    s4 = ls[0] + ls[1] + ls[2] + ls[3];
        const unsigned c4 = lc[0] + lc[1] + lc[2] + lc[3];
        if (s4 != 0.0f || c4 != 0u) {
            const int bk = (blockIdx.y * 8 + blockIdx.x) & (NBUCKET - 1);
            atomicAdd(&bsum[bk], s4);
            atomicAdd(&bcnt[bk], c4);
        }
    }
}

__global__ __launch_bounds__(256) void finalize_kernel(
    const float* __restrict__ bsum, const unsigned* __restrict__ bcnt,
    float* __restrict__ out)
{
    float    s = 0.0f;
    unsigned c = 0u;
    for (int b = threadIdx.x; b < NBUCKET; b += 256) { s += bsum[b]; c += bcnt[b]; }
    #pragma unroll
    for (int off = 32; off > 0; off >>= 1) {
        s += __shfl_xor(s, off, 64);
        c += (unsigned)__shfl_xor((int)c, off, 64);
    }
    __shared__ float    ls[4];
    __shared__ unsigned lc[4];
    const int wid = threadIdx.x >> 6, lane = threadIdx.x & 63;
    if (lane == 0) { ls[wid] = s; lc[wid] = c; }
    __syncthreads();
    if (threadIdx.x == 0) {
        const float    st = ls[0] + ls[1] + ls[2] + ls[3];
        const unsigned ct = lc[0] + lc[1] + lc[2] + lc[3];
        const unsigned n  = ct > 1u ? ct : 1u;
        out[0] = st / (float)n;
    }
}

extern "C" void kernel_launch(void* const* d_in, const int* in_sizes, int n_in,
                              void* d_out, int out_size, void* d_ws, size_t ws_size,
                              hipStream_t stream) {
    const float2* pos  = (const float2*)d_in[0];   // node_positions (8,512,2)
    // d_in[1] = adjacency: unused
    const int*    esrc = (const int*)d_in[2];       // edge_index[0]
    const int*    edst = esrc + EDGES;              // edge_index[1]

    float*    out  = (float*)d_out;
    char*     ws   = (char*)d_ws;
    float*    bsum = (float*)ws;                    // 2048 floats
    unsigned* bcnt = (unsigned*)(ws + NBUCKET * 4); // 2048 uints
    float4*   rec1 = (float4*)(ws + 65536);         // 3 x 64 KB of records
    float4*   rec2 = rec1 + EDGES;
    float4*   rec3 = rec2 + EDGES;

    hipMemsetAsync(d_ws, 0, NBUCKET * 8, stream);   // bsum + bcnt

    edge_pre<<<EDGES / 256, 256, 0, stream>>>(pos, esrc, edst, rec1, rec2, rec3);
    zero_fill<<<ZF_BLOCKS, 256, 0, stream>>>(out);
    dim3 grid(EDGES / JBLK, EDGES / ITILE);         // (8, 512)
    mask_seg<<<grid, 256, 0, stream>>>(rec1, rec2, rec3, out, bsum, bcnt);
    finalize_kernel<<<1, 256, 0, stream>>>(bsum, bcnt, out);
}